// Round 1
// baseline (544.452 us; speedup 1.0000x reference)
//
#include <hip/hip_runtime.h>
#include <hip/hip_bf16.h>
#include <math.h>

// Problem constants
#define BATCH 4
#define TLEN 8192
#define BT 32768      // BATCH*TLEN
#define DIM 512
#define TB 16         // t-rows per block in score kernel
#define CHUNK 128     // t per scan chunk
#define NCHUNK 64     // TLEN / CHUNK

// ---------------------------------------------------------------------------
// Kernel 1: s[row] = sum_e w2[e] * tanh( sum_d x[row,d]*W1[e,d] + b1[e] )
// (b2 dropped: softmax is shift-invariant, cancels exactly in num/den)
// Block: 256 threads, TB=16 rows. Thread tile: 4e x 8t register outer product.
// x tile staged in LDS (32 KB); W1 streamed from L2 (1 MB, resident).
// ---------------------------------------------------------------------------
__global__ __launch_bounds__(256) void score_kernel(
    const float* __restrict__ x, const float* __restrict__ W1,
    const float* __restrict__ b1, const float* __restrict__ w2,
    float* __restrict__ s)
{
    __shared__ float lds[TB * DIM];   // 32 KB
    const int tid = threadIdx.x;
    const long m0 = (long)blockIdx.x * TB;

    // load x tile, coalesced float4
    {
        const float4* xg = (const float4*)(x + m0 * DIM);
        float4* xl = (float4*)lds;
        #pragma unroll
        for (int i = 0; i < (TB * DIM / 4) / 256; ++i)
            xl[tid + i * 256] = xg[tid + i * 256];
    }
    __syncthreads();

    const int eg = tid >> 1;        // 0..127 -> e block of 4
    const int e0 = eg * 4;
    const int tg = tid & 1;         // 0..1   -> t half
    const int tr = tg * 8;

    float acc[4][8];
    #pragma unroll
    for (int j = 0; j < 4; ++j)
        #pragma unroll
        for (int i = 0; i < 8; ++i) acc[j][i] = 0.f;

    for (int k = 0; k < DIM; k += 4) {
        float4 w4[4];
        #pragma unroll
        for (int j = 0; j < 4; ++j)
            w4[j] = *(const float4*)(W1 + (long)(e0 + j) * DIM + k);
        float4 xq[8];
        #pragma unroll
        for (int i = 0; i < 8; ++i)
            xq[i] = *(const float4*)(lds + (tr + i) * DIM + k);
        #pragma unroll
        for (int j = 0; j < 4; ++j) {
            #pragma unroll
            for (int i = 0; i < 8; ++i) {
                acc[j][i] += w4[j].x * xq[i].x;
                acc[j][i] += w4[j].y * xq[i].y;
                acc[j][i] += w4[j].z * xq[i].z;
                acc[j][i] += w4[j].w * xq[i].w;
            }
        }
    }

    float b1v[4], w2v[4];
    #pragma unroll
    for (int j = 0; j < 4; ++j) { b1v[j] = b1[e0 + j]; w2v[j] = w2[e0 + j]; }

    float part[8];
    #pragma unroll
    for (int i = 0; i < 8; ++i) {
        float p = 0.f;
        #pragma unroll
        for (int j = 0; j < 4; ++j)
            p += w2v[j] * tanhf(acc[j][i] + b1v[j]);
        part[i] = p;
    }

    __syncthreads();   // done with x tile, repurpose LDS as s_part[128][16]
    #pragma unroll
    for (int i = 0; i < 8; ++i)
        lds[eg * TB + tr + i] = part[i];
    __syncthreads();
    if (tid < TB) {
        float sum = 0.f;
        for (int g = 0; g < 128; ++g) sum += lds[g * TB + tid];
        s[m0 + tid] = sum;
    }
}

// ---------------------------------------------------------------------------
// Kernel 2: per batch row: m = max_t s; e = exp(s-m); den = inclusive cumsum(e)
// One block (256 threads) per b; each thread owns 32 contiguous t.
// ---------------------------------------------------------------------------
__global__ __launch_bounds__(256) void scan_den_kernel(
    const float* __restrict__ s, float* __restrict__ e_out,
    float* __restrict__ den_out)
{
    __shared__ float red[256];
    const int b = blockIdx.x;
    const int tid = threadIdx.x;
    const float* sb = s + (long)b * TLEN;

    float sv[32];
    #pragma unroll
    for (int i = 0; i < 32; ++i) sv[i] = sb[tid * 32 + i];
    float lmax = sv[0];
    #pragma unroll
    for (int i = 1; i < 32; ++i) lmax = fmaxf(lmax, sv[i]);
    red[tid] = lmax;
    __syncthreads();
    for (int off = 128; off > 0; off >>= 1) {
        if (tid < off) red[tid] = fmaxf(red[tid], red[tid + off]);
        __syncthreads();
    }
    const float m = red[0];
    __syncthreads();

    float ev[32];
    float run = 0.f;
    #pragma unroll
    for (int i = 0; i < 32; ++i) {
        ev[i] = __expf(sv[i] - m);
        run += ev[i];
        sv[i] = run;               // local inclusive scan
    }
    red[tid] = run;
    __syncthreads();
    if (tid == 0) {                // serial exclusive scan over 256 totals
        float r = 0.f;
        for (int i = 0; i < 256; ++i) { float v = red[i]; red[i] = r; r += v; }
    }
    __syncthreads();
    const float off0 = red[tid];
    float* eb = e_out + (long)b * TLEN;
    float* db = den_out + (long)b * TLEN;
    #pragma unroll
    for (int i = 0; i < 32; ++i) {
        eb[tid * 32 + i] = ev[i];
        db[tid * 32 + i] = sv[i] + off0;
    }
}

// ---------------------------------------------------------------------------
// Kernel 3: chunk partial sums  csum[b,c,d] = sum_{t in chunk} e[t]*x[t,d]
// Block = (c, b), 128 threads x float4 covers D=512.
// ---------------------------------------------------------------------------
__global__ __launch_bounds__(128) void chunk_sum_kernel(
    const float* __restrict__ x, const float* __restrict__ e,
    float* __restrict__ csum)
{
    __shared__ float el[CHUNK];
    const int c = blockIdx.x, b = blockIdx.y;
    const int tid = threadIdx.x;
    el[tid] = e[(long)b * TLEN + c * CHUNK + tid];
    __syncthreads();
    const float4* xb = (const float4*)(x + ((long)b * TLEN + c * CHUNK) * DIM);
    float4 acc = {0.f, 0.f, 0.f, 0.f};
    for (int t = 0; t < CHUNK; ++t) {
        float4 xv = xb[t * (DIM / 4) + tid];
        float w = el[t];
        acc.x += w * xv.x; acc.y += w * xv.y;
        acc.z += w * xv.z; acc.w += w * xv.w;
    }
    ((float4*)(csum + ((long)(b * NCHUNK + c)) * DIM))[tid] = acc;
}

// ---------------------------------------------------------------------------
// Kernel 4: in-place exclusive scan of chunk sums over c (per b, per d)
// ---------------------------------------------------------------------------
__global__ __launch_bounds__(128) void chunk_scan_kernel(float* __restrict__ csum)
{
    const int b = blockIdx.x;
    const int tid = threadIdx.x;
    float4 run = {0.f, 0.f, 0.f, 0.f};
    for (int c = 0; c < NCHUNK; ++c) {
        float4* p = (float4*)(csum + ((long)(b * NCHUNK + c)) * DIM) + tid;
        float4 v = *p;
        *p = run;
        run.x += v.x; run.y += v.y; run.z += v.z; run.w += v.w;
    }
}

// ---------------------------------------------------------------------------
// Kernel 5: out[b,t,d] = (csum_excl[b,c,d] + running_t) / den[b,t]
// ---------------------------------------------------------------------------
__global__ __launch_bounds__(128) void context_kernel(
    const float* __restrict__ x, const float* __restrict__ e,
    const float* __restrict__ den, const float* __restrict__ csum,
    float* __restrict__ out)
{
    __shared__ float el[CHUNK], dil[CHUNK];
    const int c = blockIdx.x, b = blockIdx.y;
    const int tid = threadIdx.x;
    el[tid]  = e[(long)b * TLEN + c * CHUNK + tid];
    dil[tid] = 1.0f / den[(long)b * TLEN + c * CHUNK + tid];
    __syncthreads();
    const float4* xb = (const float4*)(x + ((long)b * TLEN + c * CHUNK) * DIM);
    float4* ob = (float4*)(out + ((long)b * TLEN + c * CHUNK) * DIM);
    float4 acc = ((const float4*)(csum + ((long)(b * NCHUNK + c)) * DIM))[tid];
    for (int t = 0; t < CHUNK; ++t) {
        float4 xv = xb[t * (DIM / 4) + tid];
        float w = el[t];
        acc.x += w * xv.x; acc.y += w * xv.y;
        acc.z += w * xv.z; acc.w += w * xv.w;
        float inv = dil[t];
        float4 o = {acc.x * inv, acc.y * inv, acc.z * inv, acc.w * inv};
        ob[t * (DIM / 4) + tid] = o;
    }
}

// ---------------------------------------------------------------------------
extern "C" void kernel_launch(void* const* d_in, const int* in_sizes, int n_in,
                              void* d_out, int out_size, void* d_ws, size_t ws_size,
                              hipStream_t stream)
{
    const float* x  = (const float*)d_in[0];   // [4,8192,512]
    const float* W1 = (const float*)d_in[1];   // [512,512]
    const float* b1 = (const float*)d_in[2];   // [512]
    const float* w2 = (const float*)d_in[3];   // [512]
    // d_in[4] = b2 scalar: softmax shift-invariant, unused.
    float* out = (float*)d_out;

    float* ws   = (float*)d_ws;
    float* s    = ws;              // [32768]
    float* e    = ws + BT;         // [32768]
    float* den  = ws + 2 * BT;     // [32768]
    float* csum = ws + 3 * BT;     // [4*64*512] = 131072

    score_kernel<<<BT / TB, 256, 0, stream>>>(x, W1, b1, w2, s);
    scan_den_kernel<<<BATCH, 256, 0, stream>>>(s, e, den);
    chunk_sum_kernel<<<dim3(NCHUNK, BATCH), 128, 0, stream>>>(x, e, csum);
    chunk_scan_kernel<<<BATCH, 128, 0, stream>>>(csum);
    context_kernel<<<dim3(NCHUNK, BATCH), 128, 0, stream>>>(x, e, den, csum, out);
}

// Round 2
// 151.723 us; speedup vs baseline: 3.5885x; 3.5885x over previous
//
#include <hip/hip_runtime.h>
#include <hip/hip_bf16.h>
#include <math.h>

// Problem constants
#define BATCH 4
#define TLEN 8192
#define BT 32768      // BATCH*TLEN
#define DIM 512
#define CHUNK 128     // t per scan chunk
#define NCHUNK 64     // TLEN / CHUNK

typedef _Float16 h8 __attribute__((ext_vector_type(8)));
typedef _Float16 h4 __attribute__((ext_vector_type(4)));
typedef float f4 __attribute__((ext_vector_type(4)));

// ---------------------------------------------------------------------------
// Kernel 0: convert x (fp32) and W1 (fp32) to fp16, packed into d_out scratch.
// hbuf layout: [0 .. BT*DIM) = x_f16, [BT*DIM .. BT*DIM + DIM*DIM) = W1_f16.
// ---------------------------------------------------------------------------
__global__ __launch_bounds__(256) void convert_kernel(
    const float* __restrict__ x, const float* __restrict__ W1,
    _Float16* __restrict__ hbuf)
{
    const long i = (long)blockIdx.x * 256 + threadIdx.x;   // float4 index
    const long XD4 = (long)BT * DIM / 4;
    const long total4 = XD4 + (long)DIM * DIM / 4;
    if (i >= total4) return;
    float4 v;
    if (i < XD4) v = ((const float4*)x)[i];
    else         v = ((const float4*)W1)[i - XD4];
    h4 o = { (_Float16)v.x, (_Float16)v.y, (_Float16)v.z, (_Float16)v.w };
    *(h4*)(hbuf + i * 4) = o;
}

// ---------------------------------------------------------------------------
// Kernel 1: s[row] = sum_e w2[e] * tanh( sum_d x[row,d]*W1[e,d] + b1[e] )
// MFMA fp16 GEMM: 512 blocks x 64 t-rows; block covers all 512 e-columns.
// 8 waves = 2(t) x 4(e); per wave 2x8 fragments of mfma_f32_16x16x32_f16.
// A-frag: row = lane&15, k = (lane>>4)*8 + j  (contiguous 16B from x_f16)
// B-frag: col = lane&15, k = (lane>>4)*8 + j  (contiguous 16B from W1_f16)
// C/D:    col = lane&15, row = (lane>>4)*4 + i
// ---------------------------------------------------------------------------
__global__ __launch_bounds__(512) void score_mfma_kernel(
    const _Float16* __restrict__ xh, const _Float16* __restrict__ wh,
    const float* __restrict__ b1, const float* __restrict__ w2,
    float* __restrict__ s)
{
    __shared__ float spart[4][64];
    const int tid  = threadIdx.x;
    const int lane = tid & 63;
    const int w    = tid >> 6;     // 0..7
    const int wt   = w >> 2;       // 0..1  t-half
    const int we   = w & 3;        // 0..3  e-quarter
    const int l15  = lane & 15;
    const int lg   = lane >> 4;    // 0..3

    const long trow0 = (long)blockIdx.x * 64 + wt * 32;

    f4 acc[2][8];
    #pragma unroll
    for (int m = 0; m < 2; ++m)
        #pragma unroll
        for (int n = 0; n < 8; ++n) acc[m][n] = (f4){0.f, 0.f, 0.f, 0.f};

    const _Float16* aptr = xh + (trow0 + l15) * DIM + lg * 8;
    const _Float16* bptr = wh + (long)(we * 128 + l15) * DIM + lg * 8;

    #pragma unroll 4
    for (int k0 = 0; k0 < DIM; k0 += 32) {
        h8 a0 = *(const h8*)(aptr + k0);
        h8 a1 = *(const h8*)(aptr + 16 * DIM + k0);
        h8 b[8];
        #pragma unroll
        for (int n = 0; n < 8; ++n)
            b[n] = *(const h8*)(bptr + (long)n * 16 * DIM + k0);
        #pragma unroll
        for (int n = 0; n < 8; ++n) {
            acc[0][n] = __builtin_amdgcn_mfma_f32_16x16x32_f16(a0, b[n], acc[0][n], 0, 0, 0);
            acc[1][n] = __builtin_amdgcn_mfma_f32_16x16x32_f16(a1, b[n], acc[1][n], 0, 0, 0);
        }
    }

    // epilogue: s-partial = sum_e w2[e]*tanh(h+b1[e]) over this lane's 8 e's
    float b1v[8], w2v[8];
    #pragma unroll
    for (int n = 0; n < 8; ++n) {
        int e = we * 128 + n * 16 + l15;
        b1v[n] = b1[e];
        w2v[n] = w2[e];
    }
    float part[2][4];
    #pragma unroll
    for (int m = 0; m < 2; ++m)
        #pragma unroll
        for (int i = 0; i < 4; ++i) {
            float p = 0.f;
            #pragma unroll
            for (int n = 0; n < 8; ++n)
                p += w2v[n] * tanhf(acc[m][n][i] + b1v[n]);
            part[m][i] = p;
        }
    // reduce across the 16 e-lanes (xor 1,2,4,8 stays in the 16-lane group)
    #pragma unroll
    for (int off = 1; off < 16; off <<= 1)
        #pragma unroll
        for (int m = 0; m < 2; ++m)
            #pragma unroll
            for (int i = 0; i < 4; ++i)
                part[m][i] += __shfl_xor(part[m][i], off);
    if (l15 == 0) {
        #pragma unroll
        for (int m = 0; m < 2; ++m)
            #pragma unroll
            for (int i = 0; i < 4; ++i)
                spart[we][wt * 32 + m * 16 + lg * 4 + i] = part[m][i];
    }
    __syncthreads();
    if (tid < 64) {
        float v = spart[0][tid] + spart[1][tid] + spart[2][tid] + spart[3][tid];
        s[(long)blockIdx.x * 64 + tid] = v;
    }
}

// ---------------------------------------------------------------------------
// Kernel 2: per batch row: m = max_t s; e = exp(s-m); den = inclusive cumsum(e)
// ---------------------------------------------------------------------------
__global__ __launch_bounds__(256) void scan_den_kernel(
    const float* __restrict__ s, float* __restrict__ e_out,
    float* __restrict__ den_out)
{
    __shared__ float red[256];
    const int b = blockIdx.x;
    const int tid = threadIdx.x;
    const float* sb = s + (long)b * TLEN;

    float sv[32];
    #pragma unroll
    for (int i = 0; i < 32; ++i) sv[i] = sb[tid * 32 + i];
    float lmax = sv[0];
    #pragma unroll
    for (int i = 1; i < 32; ++i) lmax = fmaxf(lmax, sv[i]);
    red[tid] = lmax;
    __syncthreads();
    for (int off = 128; off > 0; off >>= 1) {
        if (tid < off) red[tid] = fmaxf(red[tid], red[tid + off]);
        __syncthreads();
    }
    const float m = red[0];
    __syncthreads();

    float ev[32];
    float run = 0.f;
    #pragma unroll
    for (int i = 0; i < 32; ++i) {
        ev[i] = __expf(sv[i] - m);
        run += ev[i];
        sv[i] = run;               // local inclusive scan
    }
    red[tid] = run;
    __syncthreads();
    if (tid == 0) {                // serial exclusive scan over 256 totals
        float r = 0.f;
        for (int i = 0; i < 256; ++i) { float v = red[i]; red[i] = r; r += v; }
    }
    __syncthreads();
    const float off0 = red[tid];
    float* eb = e_out + (long)b * TLEN;
    float* db = den_out + (long)b * TLEN;
    #pragma unroll
    for (int i = 0; i < 32; ++i) {
        eb[tid * 32 + i] = ev[i];
        db[tid * 32 + i] = sv[i] + off0;
    }
}

// ---------------------------------------------------------------------------
// Kernel 3: chunk partial sums  csum[b,c,d] = sum_{t in chunk} e[t]*x[t,d]
// ---------------------------------------------------------------------------
__global__ __launch_bounds__(128) void chunk_sum_kernel(
    const float* __restrict__ x, const float* __restrict__ e,
    float* __restrict__ csum)
{
    __shared__ float el[CHUNK];
    const int c = blockIdx.x, b = blockIdx.y;
    const int tid = threadIdx.x;
    el[tid] = e[(long)b * TLEN + c * CHUNK + tid];
    __syncthreads();
    const float4* xb = (const float4*)(x + ((long)b * TLEN + c * CHUNK) * DIM);
    float4 acc = {0.f, 0.f, 0.f, 0.f};
    for (int t = 0; t < CHUNK; ++t) {
        float4 xv = xb[t * (DIM / 4) + tid];
        float w = el[t];
        acc.x += w * xv.x; acc.y += w * xv.y;
        acc.z += w * xv.z; acc.w += w * xv.w;
    }
    ((float4*)(csum + ((long)(b * NCHUNK + c)) * DIM))[tid] = acc;
}

// ---------------------------------------------------------------------------
// Kernel 4: in-place exclusive scan of chunk sums over c (per b, per d)
// ---------------------------------------------------------------------------
__global__ __launch_bounds__(128) void chunk_scan_kernel(float* __restrict__ csum)
{
    const int b = blockIdx.x;
    const int tid = threadIdx.x;
    float4 run = {0.f, 0.f, 0.f, 0.f};
    for (int c = 0; c < NCHUNK; ++c) {
        float4* p = (float4*)(csum + ((long)(b * NCHUNK + c)) * DIM) + tid;
        float4 v = *p;
        *p = run;
        run.x += v.x; run.y += v.y; run.z += v.z; run.w += v.w;
    }
}

// ---------------------------------------------------------------------------
// Kernel 5: out[b,t,d] = (csum_excl[b,c,d] + running_t) / den[b,t]
// ---------------------------------------------------------------------------
__global__ __launch_bounds__(128) void context_kernel(
    const float* __restrict__ x, const float* __restrict__ e,
    const float* __restrict__ den, const float* __restrict__ csum,
    float* __restrict__ out)
{
    __shared__ float el[CHUNK], dil[CHUNK];
    const int c = blockIdx.x, b = blockIdx.y;
    const int tid = threadIdx.x;
    el[tid]  = e[(long)b * TLEN + c * CHUNK + tid];
    dil[tid] = 1.0f / den[(long)b * TLEN + c * CHUNK + tid];
    __syncthreads();
    const float4* xb = (const float4*)(x + ((long)b * TLEN + c * CHUNK) * DIM);
    float4* ob = (float4*)(out + ((long)b * TLEN + c * CHUNK) * DIM);
    float4 acc = ((const float4*)(csum + ((long)(b * NCHUNK + c)) * DIM))[tid];
    for (int t = 0; t < CHUNK; ++t) {
        float4 xv = xb[t * (DIM / 4) + tid];
        float w = el[t];
        acc.x += w * xv.x; acc.y += w * xv.y;
        acc.z += w * xv.z; acc.w += w * xv.w;
        float inv = dil[t];
        float4 o = {acc.x * inv, acc.y * inv, acc.z * inv, acc.w * inv};
        ob[t * (DIM / 4) + tid] = o;
    }
}

// ---------------------------------------------------------------------------
extern "C" void kernel_launch(void* const* d_in, const int* in_sizes, int n_in,
                              void* d_out, int out_size, void* d_ws, size_t ws_size,
                              hipStream_t stream)
{
    const float* x  = (const float*)d_in[0];   // [4,8192,512]
    const float* W1 = (const float*)d_in[1];   // [512,512] row-major [e][d]
    const float* b1 = (const float*)d_in[2];   // [512]
    const float* w2 = (const float*)d_in[3];   // [512]
    // d_in[4] = b2 scalar: softmax shift-invariant, unused.
    float* out = (float*)d_out;

    float* ws   = (float*)d_ws;
    float* s    = ws;              // [32768]
    float* e    = ws + BT;         // [32768]
    float* den  = ws + 2 * BT;     // [32768]
    float* csum = ws + 3 * BT;     // [4*64*512] = 131072

    // fp16 operand scratch lives in d_out (67 MB); consumed by score kernel,
    // then fully overwritten by context_kernel at the end.
    _Float16* hbuf = (_Float16*)d_out;
    const _Float16* xh = hbuf;                       // 16.7M halfs
    const _Float16* wh = hbuf + (long)BT * DIM;      // 262K halfs

    const long total4 = ((long)BT * DIM + (long)DIM * DIM) / 4;
    const int convBlocks = (int)((total4 + 255) / 256);

    convert_kernel<<<convBlocks, 256, 0, stream>>>(x, W1, hbuf);
    score_mfma_kernel<<<BT / 64, 512, 0, stream>>>(xh, wh, b1, w2, s);
    scan_den_kernel<<<BATCH, 256, 0, stream>>>(s, e, den);
    chunk_sum_kernel<<<dim3(NCHUNK, BATCH), 128, 0, stream>>>(x, e, csum);
    chunk_scan_kernel<<<BATCH, 128, 0, stream>>>(csum);
    context_kernel<<<dim3(NCHUNK, BATCH), 128, 0, stream>>>(x, e, den, csum, out);
}

// Round 3
// 103.810 us; speedup vs baseline: 5.2447x; 1.4616x over previous
//
#include <hip/hip_runtime.h>
#include <hip/hip_bf16.h>
#include <math.h>

// Problem constants
#define BATCH 4
#define TLEN 8192
#define BT 32768      // BATCH*TLEN
#define DIM 512
#define CHUNK 128     // t per scan chunk
#define NCHUNK 64     // TLEN / CHUNK

// score GEMM tile
#define BM 128
#define BN 128
#define BK 32

typedef _Float16 h8 __attribute__((ext_vector_type(8)));
typedef _Float16 h4 __attribute__((ext_vector_type(4)));
typedef float f4 __attribute__((ext_vector_type(4)));

__device__ __forceinline__ void gload_lds16(const _Float16* g, _Float16* l) {
    __builtin_amdgcn_global_load_lds(
        (const __attribute__((address_space(1))) void*)g,
        (__attribute__((address_space(3))) void*)l, 16, 0, 0);
}

// ---------------------------------------------------------------------------
// Kernel 0: convert x (fp32) and W1 (fp32) to fp16, packed into d_out scratch.
// hbuf layout: [0 .. BT*DIM) = x_f16, [BT*DIM ..) = W1_f16, then spart fp32.
// ---------------------------------------------------------------------------
__global__ __launch_bounds__(256) void convert_kernel(
    const float* __restrict__ x, const float* __restrict__ W1,
    _Float16* __restrict__ hbuf)
{
    const long i = (long)blockIdx.x * 256 + threadIdx.x;   // float4 index
    const long XD4 = (long)BT * DIM / 4;
    const long total4 = XD4 + (long)DIM * DIM / 4;
    if (i >= total4) return;
    float4 v;
    if (i < XD4) v = ((const float4*)x)[i];
    else         v = ((const float4*)W1)[i - XD4];
    h4 o = { (_Float16)v.x, (_Float16)v.y, (_Float16)v.z, (_Float16)v.w };
    *(h4*)(hbuf + i * 4) = o;
}

// ---------------------------------------------------------------------------
// Kernel 1: score GEMM, m97 structure. 1024 blocks (256 t-tiles x 4 e-tiles),
// 256 threads = 4 waves (2x2), per-wave 64x64 = 4x4 frags of 16x16x32 f16.
// A,B staged to LDS via global_load_lds width-16; 2 barriers per K-step.
// Epilogue: partial s over this block's 128 e -> spart[be][row] (no atomics).
// XCD-chunked swizzle: sibling e-tiles of one t-tile share an XCD's L2.
// ---------------------------------------------------------------------------
__global__ __launch_bounds__(256) void score_mfma_kernel(
    const _Float16* __restrict__ xh, const _Float16* __restrict__ wh,
    const float* __restrict__ b1, const float* __restrict__ w2,
    float* __restrict__ spart)
{
    __shared__ _Float16 Als[BM * BK];   // 8 KB, row-major [128][32]
    __shared__ _Float16 Bls[BN * BK];   // 8 KB
    __shared__ float sred[2][BM];       // 1 KB

    // bijective XCD-chunked swizzle over 1024 blocks (1024 % 8 == 0)
    const int orig = blockIdx.x;
    const int wid  = (orig & 7) * 128 + (orig >> 3);
    const int bt = wid >> 2, be = wid & 3;
    const long trow0 = (long)bt * BM;
    const int  ecol0 = be * BN;

    const int tid  = threadIdx.x;
    const int lane = tid & 63;
    const int w    = tid >> 6;       // 0..3
    const int wr   = w >> 1;         // t-half of tile
    const int wc   = w & 1;          // e-half of tile
    const int l15  = lane & 15;
    const int lg   = lane >> 4;      // 0..3

    // staging: wave w covers rows [w*32, w*32+32) via two 1KB issues (16 rows)
    const int srow = w * 32 + (lane >> 2);
    const int skof = (lane & 3) * 8;
    const _Float16* ga = xh + (trow0 + srow) * DIM + skof;
    const _Float16* gb = wh + (long)(ecol0 + srow) * DIM + skof;
    _Float16* laA = &Als[w * 1024];          // wave-uniform LDS bases
    _Float16* laB = &Bls[w * 1024];

    f4 acc[4][4];
    #pragma unroll
    for (int m = 0; m < 4; ++m)
        #pragma unroll
        for (int n = 0; n < 4; ++n) acc[m][n] = (f4){0.f, 0.f, 0.f, 0.f};

    for (int k0 = 0; k0 < DIM; k0 += BK) {
        gload_lds16(ga + k0,            laA);
        gload_lds16(ga + 16 * DIM + k0, laA + 512);
        gload_lds16(gb + k0,            laB);
        gload_lds16(gb + 16 * DIM + k0, laB + 512);
        __syncthreads();                 // vmcnt(0) drain + all waves staged

        h8 a[4], bf[4];
        #pragma unroll
        for (int m = 0; m < 4; ++m)
            a[m] = *(const h8*)&Als[(wr * 64 + m * 16 + l15) * BK + lg * 8];
        #pragma unroll
        for (int n = 0; n < 4; ++n)
            bf[n] = *(const h8*)&Bls[(wc * 64 + n * 16 + l15) * BK + lg * 8];
        #pragma unroll
        for (int m = 0; m < 4; ++m)
            #pragma unroll
            for (int n = 0; n < 4; ++n)
                acc[m][n] = __builtin_amdgcn_mfma_f32_16x16x32_f16(
                    a[m], bf[n], acc[m][n], 0, 0, 0);
        __syncthreads();                 // frags consumed before restage
    }

    // epilogue: p = sum over this lane's 4 e's of w2*tanh(h + b1)
    float b1v[4], w2v[4];
    #pragma unroll
    for (int n = 0; n < 4; ++n) {
        int e = ecol0 + wc * 64 + n * 16 + l15;
        b1v[n] = b1[e];
        w2v[n] = w2[e];
    }
    float pp[4][4];
    #pragma unroll
    for (int m = 0; m < 4; ++m)
        #pragma unroll
        for (int i = 0; i < 4; ++i) {
            float p = 0.f;
            #pragma unroll
            for (int n = 0; n < 4; ++n)
                p += w2v[n] * tanhf(acc[m][n][i] + b1v[n]);
            pp[m][i] = p;
        }
    // reduce across the 16 e-lanes of each lane-group
    #pragma unroll
    for (int off = 1; off < 16; off <<= 1)
        #pragma unroll
        for (int m = 0; m < 4; ++m)
            #pragma unroll
            for (int i = 0; i < 4; ++i)
                pp[m][i] += __shfl_xor(pp[m][i], off);
    if (l15 == 0) {
        #pragma unroll
        for (int m = 0; m < 4; ++m)
            #pragma unroll
            for (int i = 0; i < 4; ++i)
                sred[wc][wr * 64 + m * 16 + lg * 4 + i] = pp[m][i];
    }
    __syncthreads();
    if (tid < BM)
        spart[(long)be * BT + trow0 + tid] = sred[0][tid] + sred[1][tid];
}

// ---------------------------------------------------------------------------
// Kernel 2: per batch row: s = sum of 4 spart segments; m = max; e = exp(s-m);
// den = inclusive cumsum(e). Hillis-Steele LDS scan for the 256 totals.
// ---------------------------------------------------------------------------
__global__ __launch_bounds__(256) void scan_den_kernel(
    const float* __restrict__ spart, float* __restrict__ e_out,
    float* __restrict__ den_out)
{
    __shared__ float red[256];
    const int b = blockIdx.x;
    const int tid = threadIdx.x;
    const long base = (long)b * TLEN + tid * 32;

    float sv[32];
    #pragma unroll
    for (int i = 0; i < 32; ++i)
        sv[i] = spart[base + i] + spart[BT + base + i]
              + spart[2l * BT + base + i] + spart[3l * BT + base + i];

    float lmax = sv[0];
    #pragma unroll
    for (int i = 1; i < 32; ++i) lmax = fmaxf(lmax, sv[i]);
    red[tid] = lmax;
    __syncthreads();
    for (int off = 128; off > 0; off >>= 1) {
        if (tid < off) red[tid] = fmaxf(red[tid], red[tid + off]);
        __syncthreads();
    }
    const float m = red[0];
    __syncthreads();

    float ev[32];
    float run = 0.f;
    #pragma unroll
    for (int i = 0; i < 32; ++i) {
        ev[i] = __expf(sv[i] - m);
        run += ev[i];
        sv[i] = run;               // local inclusive scan
    }
    red[tid] = run;
    __syncthreads();
    // Hillis-Steele inclusive scan of the 256 thread totals
    for (int off = 1; off < 256; off <<= 1) {
        float u = (tid >= off) ? red[tid - off] : 0.f;
        __syncthreads();
        red[tid] += u;
        __syncthreads();
    }
    const float off0 = red[tid] - run;   // exclusive prefix
    float* eb = e_out + (long)b * TLEN;
    float* db = den_out + (long)b * TLEN;
    #pragma unroll
    for (int i = 0; i < 32; ++i) {
        eb[tid * 32 + i] = ev[i];
        db[tid * 32 + i] = sv[i] + off0;
    }
}

// ---------------------------------------------------------------------------
// Kernel 3: chunk partial sums  csum[b,c,d] = sum_{t in chunk} e[t]*xh[t,d]
// (reads fp16 xh -> half the traffic of fp32 x; fp32 accumulate)
// ---------------------------------------------------------------------------
__global__ __launch_bounds__(128) void chunk_sum_kernel(
    const _Float16* __restrict__ xh, const float* __restrict__ e,
    float* __restrict__ csum)
{
    __shared__ float el[CHUNK];
    const int c = blockIdx.x, b = blockIdx.y;
    const int tid = threadIdx.x;
    el[tid] = e[(long)b * TLEN + c * CHUNK + tid];
    __syncthreads();
    const _Float16* xb = xh + ((long)b * TLEN + c * CHUNK) * DIM;
    float a0 = 0.f, a1 = 0.f, a2 = 0.f, a3 = 0.f;
    for (int t = 0; t < CHUNK; ++t) {
        h4 xv = *(const h4*)(xb + (long)t * DIM + tid * 4);
        float wgt = el[t];
        a0 += wgt * (float)xv[0];
        a1 += wgt * (float)xv[1];
        a2 += wgt * (float)xv[2];
        a3 += wgt * (float)xv[3];
    }
    float4 o = {a0, a1, a2, a3};
    ((float4*)(csum + ((long)(b * NCHUNK + c)) * DIM))[tid] = o;
}

// ---------------------------------------------------------------------------
// Kernel 4: in-place exclusive scan of chunk sums over c (per b, per d).
// 512 threads = 1 d-float each; unroll lets loads run ahead of the add chain.
// ---------------------------------------------------------------------------
__global__ __launch_bounds__(512) void chunk_scan_kernel(float* __restrict__ csum)
{
    const int b = blockIdx.x;
    const int d = threadIdx.x;
    float run = 0.f;
    #pragma unroll 8
    for (int c = 0; c < NCHUNK; ++c) {
        float* p = csum + ((long)(b * NCHUNK + c)) * DIM + d;
        float v = *p;
        *p = run;
        run += v;
    }
}

// ---------------------------------------------------------------------------
// Kernel 5: out[b,t,d] = (csum_excl[b,c,d] + running_t) / den[b,t]
// (reads fp32 x: d_out scratch is being overwritten by this kernel)
// ---------------------------------------------------------------------------
__global__ __launch_bounds__(128) void context_kernel(
    const float* __restrict__ x, const float* __restrict__ e,
    const float* __restrict__ den, const float* __restrict__ csum,
    float* __restrict__ out)
{
    __shared__ float el[CHUNK], dil[CHUNK];
    const int c = blockIdx.x, b = blockIdx.y;
    const int tid = threadIdx.x;
    el[tid]  = e[(long)b * TLEN + c * CHUNK + tid];
    dil[tid] = 1.0f / den[(long)b * TLEN + c * CHUNK + tid];
    __syncthreads();
    const float4* xb = (const float4*)(x + ((long)b * TLEN + c * CHUNK) * DIM);
    float4* ob = (float4*)(out + ((long)b * TLEN + c * CHUNK) * DIM);
    float4 acc = ((const float4*)(csum + ((long)(b * NCHUNK + c)) * DIM))[tid];
    for (int t = 0; t < CHUNK; ++t) {
        float4 xv = xb[t * (DIM / 4) + tid];
        float wv = el[t];
        acc.x += wv * xv.x; acc.y += wv * xv.y;
        acc.z += wv * xv.z; acc.w += wv * xv.w;
        float inv = dil[t];
        float4 o = {acc.x * inv, acc.y * inv, acc.z * inv, acc.w * inv};
        ob[t * (DIM / 4) + tid] = o;
    }
}

// ---------------------------------------------------------------------------
extern "C" void kernel_launch(void* const* d_in, const int* in_sizes, int n_in,
                              void* d_out, int out_size, void* d_ws, size_t ws_size,
                              hipStream_t stream)
{
    const float* x  = (const float*)d_in[0];   // [4,8192,512]
    const float* W1 = (const float*)d_in[1];   // [512,512] row-major [e][d]
    const float* b1 = (const float*)d_in[2];   // [512]
    const float* w2 = (const float*)d_in[3];   // [512]
    // d_in[4] = b2 scalar: softmax shift-invariant, unused.
    float* out = (float*)d_out;

    float* ws   = (float*)d_ws;
    float* e    = ws;              // [32768]
    float* den  = ws + BT;         // [32768]
    float* csum = ws + 2 * BT;     // [4*64*512] = 131072

    // fp16 operands + spart live in d_out (67 MB): consumed before the final
    // context_kernel overwrites d_out with the real output.
    _Float16* hbuf = (_Float16*)d_out;
    const _Float16* xh = hbuf;                              // 16.7M halfs
    const _Float16* wh = hbuf + (long)BT * DIM;             // 262K halfs
    float* spart = (float*)(hbuf + (long)BT * DIM + DIM * DIM);  // [4][32768]

    const long total4 = ((long)BT * DIM + (long)DIM * DIM) / 4;
    const int convBlocks = (int)((total4 + 255) / 256);

    convert_kernel<<<convBlocks, 256, 0, stream>>>(x, W1, hbuf);
    score_mfma_kernel<<<(BT / BM) * 4, 256, 0, stream>>>(xh, wh, b1, w2, spart);
    scan_den_kernel<<<BATCH, 256, 0, stream>>>(spart, e, den);
    chunk_sum_kernel<<<dim3(NCHUNK, BATCH), 128, 0, stream>>>(xh, e, csum);
    chunk_scan_kernel<<<BATCH, 512, 0, stream>>>(csum);
    context_kernel<<<dim3(NCHUNK, BATCH), 128, 0, stream>>>(x, e, den, csum, out);
}

// Round 4
// 95.835 us; speedup vs baseline: 5.6811x; 1.0832x over previous
//
#include <hip/hip_runtime.h>
#include <hip/hip_bf16.h>
#include <math.h>

// Problem constants
#define BATCH 4
#define TLEN 8192
#define BT 32768      // BATCH*TLEN
#define DIM 512
#define CHUNK 128     // t per scan chunk
#define NCHUNK 64     // TLEN / CHUNK

// score GEMM tile
#define BM 128
#define BN 128
#define BK 32

typedef _Float16 h8 __attribute__((ext_vector_type(8)));
typedef _Float16 h4 __attribute__((ext_vector_type(4)));
typedef float f4 __attribute__((ext_vector_type(4)));

__device__ __forceinline__ void gload_lds16(const _Float16* g, _Float16* l) {
    __builtin_amdgcn_global_load_lds(
        (const __attribute__((address_space(1))) void*)g,
        (__attribute__((address_space(3))) void*)l, 16, 0, 0);
}

// fast tanh: 1 - 2/(e^{2z}+1). |err| ~1e-6; saturates correctly at +-1.
__device__ __forceinline__ float fast_tanh(float z) {
    float u = __expf(2.0f * z);
    return 1.0f - __fdividef(2.0f, u + 1.0f);
}

// ---------------------------------------------------------------------------
// Kernel 0: convert x (fp32) and W1 (fp32) to fp16, packed into d_out scratch.
// Linear row-major layout (swizzle is applied at staging/read time in score).
// ---------------------------------------------------------------------------
__global__ __launch_bounds__(256) void convert_kernel(
    const float* __restrict__ x, const float* __restrict__ W1,
    _Float16* __restrict__ hbuf)
{
    const long i = (long)blockIdx.x * 256 + threadIdx.x;   // float4 index
    const long XD4 = (long)BT * DIM / 4;
    const long total4 = XD4 + (long)DIM * DIM / 4;
    if (i >= total4) return;
    float4 v;
    if (i < XD4) v = ((const float4*)x)[i];
    else         v = ((const float4*)W1)[i - XD4];
    h4 o = { (_Float16)v.x, (_Float16)v.y, (_Float16)v.z, (_Float16)v.w };
    *(h4*)(hbuf + i * 4) = o;
}

// ---------------------------------------------------------------------------
// Kernel 1: score GEMM, prefetch-double-buffered m97 structure.
// 1024 blocks (256 t-tiles x 4 e-tiles), 256 threads = 4 waves (2x2),
// per-wave 64x64 = 4x4 frags of 16x16x32 f16.
// Per K-step: STAGE(next buf) -> ds_read(cur) -> 16 MFMA -> syncthreads
// (vmcnt(0)+barrier at the BOTTOM: prefetch latency hides under MFMA).
// 16B-group XOR swizzle (g ^= row&3) on stage-source AND frag-read: 8->4-way.
// Epilogue: fast-tanh + w2 reduce -> spart[be][row] (no atomics).
// ---------------------------------------------------------------------------
__global__ __launch_bounds__(256, 3) void score_mfma_kernel(
    const _Float16* __restrict__ xh, const _Float16* __restrict__ wh,
    const float* __restrict__ b1, const float* __restrict__ w2,
    float* __restrict__ spart)
{
    __shared__ _Float16 Als[2][BM * BK];   // 2 x 8 KB
    __shared__ _Float16 Bls[2][BM * BK];   // 2 x 8 KB
    __shared__ float sred[2][BM];          // 1 KB

    // bijective XCD-chunked swizzle over 1024 blocks (1024 % 8 == 0)
    const int orig = blockIdx.x;
    const int wid  = (orig & 7) * 128 + (orig >> 3);
    const int bt = wid >> 2, be = wid & 3;
    const long trow0 = (long)bt * BM;
    const int  ecol0 = be * BN;

    const int tid  = threadIdx.x;
    const int lane = tid & 63;
    const int w    = tid >> 6;       // 0..3
    const int wr   = w >> 1;         // t-half of tile
    const int wc   = w & 1;          // e-half of tile
    const int l15  = lane & 15;
    const int lg   = lane >> 4;      // 0..3

    // staging: wave w covers rows [w*32, w*32+32), 8 rows per 1KB issue pair.
    // source 16B-group = (lane&3) ^ (srow&3)  (involution; read applies same)
    const int srow = w * 32 + (lane >> 2);
    const int skof = ((lane & 3) ^ (srow & 3)) * 8;
    const _Float16* ga = xh + (trow0 + srow) * DIM + skof;
    const _Float16* gb = wh + (long)(ecol0 + srow) * DIM + skof;
    _Float16* laA0 = &Als[0][w * 1024];
    _Float16* laB0 = &Bls[0][w * 1024];
    _Float16* laA1 = &Als[1][w * 1024];
    _Float16* laB1 = &Bls[1][w * 1024];

    // frag-read swizzled k-offset: constant per lane (row&3 == l15&3)
    const int koff = (lg ^ (l15 & 3)) * 8;

    f4 acc[4][4];
    #pragma unroll
    for (int m = 0; m < 4; ++m)
        #pragma unroll
        for (int n = 0; n < 4; ++n) acc[m][n] = (f4){0.f, 0.f, 0.f, 0.f};

#define STAGE(A_, B_, k0_) {                         \
    gload_lds16(ga + (k0_),            (A_));        \
    gload_lds16(ga + 16 * DIM + (k0_), (A_) + 512);  \
    gload_lds16(gb + (k0_),            (B_));        \
    gload_lds16(gb + 16 * DIM + (k0_), (B_) + 512);  }

#define COMPUTE(bsel_) {                                                      \
    h8 afr[4], bfr[4];                                                        \
    _Pragma("unroll")                                                         \
    for (int m = 0; m < 4; ++m)                                               \
        afr[m] = *(const h8*)&Als[bsel_][(wr * 64 + m * 16 + l15) * BK + koff]; \
    _Pragma("unroll")                                                         \
    for (int n = 0; n < 4; ++n)                                               \
        bfr[n] = *(const h8*)&Bls[bsel_][(wc * 64 + n * 16 + l15) * BK + koff]; \
    _Pragma("unroll")                                                         \
    for (int m = 0; m < 4; ++m)                                               \
        _Pragma("unroll")                                                     \
        for (int n = 0; n < 4; ++n)                                           \
            acc[m][n] = __builtin_amdgcn_mfma_f32_16x16x32_f16(               \
                afr[m], bfr[n], acc[m][n], 0, 0, 0);                          }

    STAGE(laA0, laB0, 0);
    __syncthreads();                       // drain prologue stage
    int cur = 0;
    #pragma unroll 2
    for (int s = 0; s < 15; ++s) {
        // prefetch next K-step into the other buffer, then compute current
        if (cur == 0) { STAGE(laA1, laB1, (s + 1) * BK); }
        else          { STAGE(laA0, laB0, (s + 1) * BK); }
        COMPUTE(cur);
        __syncthreads();                   // vmcnt(0): prefetch landed; reads done
        cur ^= 1;
    }
    COMPUTE(cur);                          // last step, nothing left to stage

    // epilogue: p = sum over this lane's 4 e's of w2*tanh(h + b1)
    float b1v[4], w2v[4];
    #pragma unroll
    for (int n = 0; n < 4; ++n) {
        int e = ecol0 + wc * 64 + n * 16 + l15;
        b1v[n] = b1[e];
        w2v[n] = w2[e];
    }
    float pp[4][4];
    #pragma unroll
    for (int m = 0; m < 4; ++m)
        #pragma unroll
        for (int i = 0; i < 4; ++i) {
            float p = 0.f;
            #pragma unroll
            for (int n = 0; n < 4; ++n)
                p += w2v[n] * fast_tanh(acc[m][n][i] + b1v[n]);
            pp[m][i] = p;
        }
    // reduce across the 16 e-lanes of each lane-group
    #pragma unroll
    for (int off = 1; off < 16; off <<= 1)
        #pragma unroll
        for (int m = 0; m < 4; ++m)
            #pragma unroll
            for (int i = 0; i < 4; ++i)
                pp[m][i] += __shfl_xor(pp[m][i], off);
    __syncthreads();                       // all MFMA/LDS traffic done
    if (l15 == 0) {
        #pragma unroll
        for (int m = 0; m < 4; ++m)
            #pragma unroll
            for (int i = 0; i < 4; ++i)
                sred[wc][wr * 64 + m * 16 + lg * 4 + i] = pp[m][i];
    }
    __syncthreads();
    if (tid < BM)
        spart[(long)be * BT + trow0 + tid] = sred[0][tid] + sred[1][tid];
}

// ---------------------------------------------------------------------------
// Kernel 2: per batch row: s = sum of 4 spart segments; m = max; e = exp(s-m);
// den = inclusive cumsum(e). Hillis-Steele LDS scan for the 256 totals.
// ---------------------------------------------------------------------------
__global__ __launch_bounds__(256) void scan_den_kernel(
    const float* __restrict__ spart, float* __restrict__ e_out,
    float* __restrict__ den_out)
{
    __shared__ float red[256];
    const int b = blockIdx.x;
    const int tid = threadIdx.x;
    const long base = (long)b * TLEN + tid * 32;

    float sv[32];
    #pragma unroll
    for (int i = 0; i < 32; ++i)
        sv[i] = spart[base + i] + spart[BT + base + i]
              + spart[2l * BT + base + i] + spart[3l * BT + base + i];

    float lmax = sv[0];
    #pragma unroll
    for (int i = 1; i < 32; ++i) lmax = fmaxf(lmax, sv[i]);
    red[tid] = lmax;
    __syncthreads();
    for (int off = 128; off > 0; off >>= 1) {
        if (tid < off) red[tid] = fmaxf(red[tid], red[tid + off]);
        __syncthreads();
    }
    const float m = red[0];
    __syncthreads();

    float ev[32];
    float run = 0.f;
    #pragma unroll
    for (int i = 0; i < 32; ++i) {
        ev[i] = __expf(sv[i] - m);
        run += ev[i];
        sv[i] = run;               // local inclusive scan
    }
    red[tid] = run;
    __syncthreads();
    // Hillis-Steele inclusive scan of the 256 thread totals
    for (int off = 1; off < 256; off <<= 1) {
        float u = (tid >= off) ? red[tid - off] : 0.f;
        __syncthreads();
        red[tid] += u;
        __syncthreads();
    }
    const float off0 = red[tid] - run;   // exclusive prefix
    float* eb = e_out + (long)b * TLEN;
    float* db = den_out + (long)b * TLEN;
    #pragma unroll
    for (int i = 0; i < 32; ++i) {
        eb[tid * 32 + i] = ev[i];
        db[tid * 32 + i] = sv[i] + off0;
    }
}

// ---------------------------------------------------------------------------
// Kernel 3: chunk partial sums  csum[b,c,d] = sum_{t in chunk} e[t]*xh[t,d]
// (reads fp16 xh -> half the traffic of fp32 x; fp32 accumulate)
// ---------------------------------------------------------------------------
__global__ __launch_bounds__(128) void chunk_sum_kernel(
    const _Float16* __restrict__ xh, const float* __restrict__ e,
    float* __restrict__ csum)
{
    __shared__ float el[CHUNK];
    const int c = blockIdx.x, b = blockIdx.y;
    const int tid = threadIdx.x;
    el[tid] = e[(long)b * TLEN + c * CHUNK + tid];
    __syncthreads();
    const _Float16* xb = xh + ((long)b * TLEN + c * CHUNK) * DIM;
    float a0 = 0.f, a1 = 0.f, a2 = 0.f, a3 = 0.f;
    for (int t = 0; t < CHUNK; ++t) {
        h4 xv = *(const h4*)(xb + (long)t * DIM + tid * 4);
        float wgt = el[t];
        a0 += wgt * (float)xv[0];
        a1 += wgt * (float)xv[1];
        a2 += wgt * (float)xv[2];
        a3 += wgt * (float)xv[3];
    }
    float4 o = {a0, a1, a2, a3};
    ((float4*)(csum + ((long)(b * NCHUNK + c)) * DIM))[tid] = o;
}

// ---------------------------------------------------------------------------
// Kernel 4: in-place exclusive scan of chunk sums over c (per b, per d).
// ---------------------------------------------------------------------------
__global__ __launch_bounds__(512) void chunk_scan_kernel(float* __restrict__ csum)
{
    const int b = blockIdx.x;
    const int d = threadIdx.x;
    float run = 0.f;
    #pragma unroll 8
    for (int c = 0; c < NCHUNK; ++c) {
        float* p = csum + ((long)(b * NCHUNK + c)) * DIM + d;
        float v = *p;
        *p = run;
        run += v;
    }
}

// ---------------------------------------------------------------------------
// Kernel 5: out[b,t,d] = (csum_excl[b,c,d] + running_t) / den[b,t]
// (reads fp32 x: d_out scratch is being overwritten by this kernel)
// ---------------------------------------------------------------------------
__global__ __launch_bounds__(128) void context_kernel(
    const float* __restrict__ x, const float* __restrict__ e,
    const float* __restrict__ den, const float* __restrict__ csum,
    float* __restrict__ out)
{
    __shared__ float el[CHUNK], dil[CHUNK];
    const int c = blockIdx.x, b = blockIdx.y;
    const int tid = threadIdx.x;
    el[tid]  = e[(long)b * TLEN + c * CHUNK + tid];
    dil[tid] = 1.0f / den[(long)b * TLEN + c * CHUNK + tid];
    __syncthreads();
    const float4* xb = (const float4*)(x + ((long)b * TLEN + c * CHUNK) * DIM);
    float4* ob = (float4*)(out + ((long)b * TLEN + c * CHUNK) * DIM);
    float4 acc = ((const float4*)(csum + ((long)(b * NCHUNK + c)) * DIM))[tid];
    for (int t = 0; t < CHUNK; ++t) {
        float4 xv = xb[t * (DIM / 4) + tid];
        float wv = el[t];
        acc.x += wv * xv.x; acc.y += wv * xv.y;
        acc.z += wv * xv.z; acc.w += wv * xv.w;
        float inv = dil[t];
        float4 o = {acc.x * inv, acc.y * inv, acc.z * inv, acc.w * inv};
        ob[t * (DIM / 4) + tid] = o;
    }
}

// ---------------------------------------------------------------------------
extern "C" void kernel_launch(void* const* d_in, const int* in_sizes, int n_in,
                              void* d_out, int out_size, void* d_ws, size_t ws_size,
                              hipStream_t stream)
{
    const float* x  = (const float*)d_in[0];   // [4,8192,512]
    const float* W1 = (const float*)d_in[1];   // [512,512] row-major [e][d]
    const float* b1 = (const float*)d_in[2];   // [512]
    const float* w2 = (const float*)d_in[3];   // [512]
    // d_in[4] = b2 scalar: softmax shift-invariant, unused.
    float* out = (float*)d_out;

    float* ws   = (float*)d_ws;
    float* e    = ws;              // [32768]
    float* den  = ws + BT;         // [32768]
    float* csum = ws + 2 * BT;     // [4*64*512] = 131072

    // fp16 operands + spart live in d_out (67 MB): consumed before the final
    // context_kernel overwrites d_out with the real output.
    _Float16* hbuf = (_Float16*)d_out;
    const _Float16* xh = hbuf;                              // 16.7M halfs
    const _Float16* wh = hbuf + (long)BT * DIM;             // 262K halfs
    float* spart = (float*)(hbuf + (long)BT * DIM + DIM * DIM);  // [4][32768]

    const long total4 = ((long)BT * DIM + (long)DIM * DIM) / 4;
    const int convBlocks = (int)((total4 + 255) / 256);

    convert_kernel<<<convBlocks, 256, 0, stream>>>(x, W1, hbuf);
    score_mfma_kernel<<<(BT / BM) * 4, 256, 0, stream>>>(xh, wh, b1, w2, spart);
    scan_den_kernel<<<BATCH, 256, 0, stream>>>(spart, e, den);
    chunk_sum_kernel<<<dim3(NCHUNK, BATCH), 128, 0, stream>>>(xh, e, csum);
    chunk_scan_kernel<<<BATCH, 512, 0, stream>>>(csum);
    context_kernel<<<dim3(NCHUNK, BATCH), 128, 0, stream>>>(x, e, den, csum, out);
}

// Round 5
// 83.472 us; speedup vs baseline: 6.5226x; 1.1481x over previous
//
#include <hip/hip_runtime.h>
#include <hip/hip_bf16.h>
#include <math.h>

// Problem constants
#define BATCH 4
#define TLEN 8192
#define BT 32768      // BATCH*TLEN
#define DIM 512
#define CHUNK 128     // t per scan chunk
#define NCHUNK 64     // TLEN / CHUNK

// score GEMM tile
#define BM 128
#define BN 128
#define BK 32

typedef _Float16 h8 __attribute__((ext_vector_type(8)));
typedef _Float16 h4 __attribute__((ext_vector_type(4)));
typedef float f4 __attribute__((ext_vector_type(4)));

__device__ __forceinline__ void gload_lds16(const _Float16* g, _Float16* l) {
    __builtin_amdgcn_global_load_lds(
        (const __attribute__((address_space(1))) void*)g,
        (__attribute__((address_space(3))) void*)l, 16, 0, 0);
}

// fast tanh: 1 - 2/(e^{2z}+1). |err| ~1e-6; saturates correctly at +-1.
__device__ __forceinline__ float fast_tanh(float z) {
    float u = __expf(2.0f * z);
    return 1.0f - __fdividef(2.0f, u + 1.0f);
}

// ---------------------------------------------------------------------------
// Kernel 0: convert x (fp32) and W1 (fp32) to fp16, packed into d_out scratch.
// ---------------------------------------------------------------------------
__global__ __launch_bounds__(256) void convert_kernel(
    const float* __restrict__ x, const float* __restrict__ W1,
    _Float16* __restrict__ hbuf)
{
    const long i = (long)blockIdx.x * 256 + threadIdx.x;   // float4 index
    const long XD4 = (long)BT * DIM / 4;
    const long total4 = XD4 + (long)DIM * DIM / 4;
    if (i >= total4) return;
    float4 v;
    if (i < XD4) v = ((const float4*)x)[i];
    else         v = ((const float4*)W1)[i - XD4];
    h4 o = { (_Float16)v.x, (_Float16)v.y, (_Float16)v.z, (_Float16)v.w };
    *(h4*)(hbuf + i * 4) = o;
}

// ---------------------------------------------------------------------------
// Kernel 1: score GEMM, counted-vmcnt pipeline (T3/T4 minimum).
// Per K-step: STAGE(s+1) -> vmcnt(4) -> barrier -> ds_read+MFMA ->
// lgkmcnt(0) -> barrier.  vmcnt(4) waits only stage s; stage s+1 stays in
// flight across the entire step (never drain to 0 in the loop).
// b1/w2 preloaded + vmcnt(0) fence BEFORE the prologue so the loop's vmcnt
// count (4 loads per stage) is exact.
// ---------------------------------------------------------------------------
__global__ __launch_bounds__(256, 4) void score_mfma_kernel(
    const _Float16* __restrict__ xh, const _Float16* __restrict__ wh,
    const float* __restrict__ b1, const float* __restrict__ w2,
    float* __restrict__ spart)
{
    __shared__ _Float16 Als[2][BM * BK];   // 2 x 8 KB
    __shared__ _Float16 Bls[2][BM * BK];   // 2 x 8 KB
    __shared__ float sred[2][BM];          // 1 KB

    // bijective XCD-chunked swizzle over 1024 blocks (1024 % 8 == 0)
    const int orig = blockIdx.x;
    const int wid  = (orig & 7) * 128 + (orig >> 3);
    const int bt = wid >> 2, be = wid & 3;
    const long trow0 = (long)bt * BM;
    const int  ecol0 = be * BN;

    const int tid  = threadIdx.x;
    const int lane = tid & 63;
    const int w    = tid >> 6;       // 0..3
    const int wr   = w >> 1;         // t-half of tile
    const int wc   = w & 1;          // e-half of tile
    const int l15  = lane & 15;
    const int lg   = lane >> 4;      // 0..3

    // staging: wave w covers rows [w*32, w*32+32), 8 rows per 1KB issue pair.
    // source 16B-group = (lane&3) ^ (srow&3)  (involution; read applies same)
    const int srow = w * 32 + (lane >> 2);
    const int skof = ((lane & 3) ^ (srow & 3)) * 8;
    const _Float16* ga = xh + (trow0 + srow) * DIM + skof;
    const _Float16* gb = wh + (long)(ecol0 + srow) * DIM + skof;
    _Float16* laA0 = &Als[0][w * 1024];
    _Float16* laB0 = &Bls[0][w * 1024];
    _Float16* laA1 = &Als[1][w * 1024];
    _Float16* laB1 = &Bls[1][w * 1024];

    // frag-read swizzled k-offset: constant per lane (row&3 == l15&3)
    const int koff = (lg ^ (l15 & 3)) * 8;

    // preload epilogue operands BEFORE the pipeline so loop vmcnt is exact
    float b1v[4], w2v[4];
    #pragma unroll
    for (int n = 0; n < 4; ++n) {
        int e = ecol0 + wc * 64 + n * 16 + l15;
        b1v[n] = b1[e];
        w2v[n] = w2[e];
    }
    asm volatile("s_waitcnt vmcnt(0)" ::: "memory");

    f4 acc[4][4];
    #pragma unroll
    for (int m = 0; m < 4; ++m)
        #pragma unroll
        for (int n = 0; n < 4; ++n) acc[m][n] = (f4){0.f, 0.f, 0.f, 0.f};

#define STAGE(A_, B_, k0_) {                         \
    gload_lds16(ga + (k0_),            (A_));        \
    gload_lds16(ga + 16 * DIM + (k0_), (A_) + 512);  \
    gload_lds16(gb + (k0_),            (B_));        \
    gload_lds16(gb + 16 * DIM + (k0_), (B_) + 512);  }

#define COMPUTE(bsel_) {                                                      \
    h8 afr[4], bfr[4];                                                        \
    _Pragma("unroll")                                                         \
    for (int m = 0; m < 4; ++m)                                               \
        afr[m] = *(const h8*)&Als[bsel_][(wr * 64 + m * 16 + l15) * BK + koff]; \
    _Pragma("unroll")                                                         \
    for (int n = 0; n < 4; ++n)                                               \
        bfr[n] = *(const h8*)&Bls[bsel_][(wc * 64 + n * 16 + l15) * BK + koff]; \
    _Pragma("unroll")                                                         \
    for (int m = 0; m < 4; ++m)                                               \
        _Pragma("unroll")                                                     \
        for (int n = 0; n < 4; ++n)                                           \
            acc[m][n] = __builtin_amdgcn_mfma_f32_16x16x32_f16(               \
                afr[m], bfr[n], acc[m][n], 0, 0, 0);                          }

    STAGE(laA0, laB0, 0);                          // stage 0 in flight (4)
    #pragma unroll 2
    for (int s = 0; s < 15; ++s) {
        // issue stage s+1 -> 8 outstanding; vmcnt(4) waits only stage s
        if (s & 1) { STAGE(laA0, laB0, (s + 1) * BK); }
        else       { STAGE(laA1, laB1, (s + 1) * BK); }
        asm volatile("s_waitcnt vmcnt(4)" ::: "memory");
        __builtin_amdgcn_s_barrier();
        if (s & 1) { COMPUTE(1); } else { COMPUTE(0); }
        asm volatile("s_waitcnt lgkmcnt(0)" ::: "memory");  // reads done
        __builtin_amdgcn_s_barrier();              // buffer s&1 now restageable
    }
    asm volatile("s_waitcnt vmcnt(0)" ::: "memory");   // drain stage 15
    __builtin_amdgcn_s_barrier();
    COMPUTE(1);                                    // s=15 -> buffer 1

    // epilogue: p = sum over this lane's 4 e's of w2*tanh(h + b1)
    float pp[4][4];
    #pragma unroll
    for (int m = 0; m < 4; ++m)
        #pragma unroll
        for (int i = 0; i < 4; ++i) {
            float p = 0.f;
            #pragma unroll
            for (int n = 0; n < 4; ++n)
                p += w2v[n] * fast_tanh(acc[m][n][i] + b1v[n]);
            pp[m][i] = p;
        }
    // reduce across the 16 e-lanes of each lane-group
    #pragma unroll
    for (int off = 1; off < 16; off <<= 1)
        #pragma unroll
        for (int m = 0; m < 4; ++m)
            #pragma unroll
            for (int i = 0; i < 4; ++i)
                pp[m][i] += __shfl_xor(pp[m][i], off);
    __syncthreads();
    if (l15 == 0) {
        #pragma unroll
        for (int m = 0; m < 4; ++m)
            #pragma unroll
            for (int i = 0; i < 4; ++i)
                sred[wc][wr * 64 + m * 16 + lg * 4 + i] = pp[m][i];
    }
    __syncthreads();
    if (tid < BM)
        spart[(long)be * BT + trow0 + tid] = sred[0][tid] + sred[1][tid];
}

// ---------------------------------------------------------------------------
// Kernel 2: chunk_sum'. No global max needed (softmax shift-invariant; |s| is
// bounded by ||w2||_1 ~ 28 so exp(s) can't overflow fp32).
// Per (c,b) block: s[t] = sum_be spart[be][t] (written to ws for context'),
// e[t] = exp(s[t]); csum[b,c,d] = sum_t e[t]*xh[t,d]; esum[b,c] = sum_t e[t].
// ---------------------------------------------------------------------------
__global__ __launch_bounds__(128) void chunk_sum_kernel(
    const _Float16* __restrict__ xh, const float* __restrict__ spart,
    float* __restrict__ s_ws, float* __restrict__ csum,
    float* __restrict__ esum)
{
    __shared__ float el[CHUNK];
    __shared__ float wred[2];
    const int c = blockIdx.x, b = blockIdx.y;
    const int tid = threadIdx.x;
    const long bt = (long)b * TLEN + c * CHUNK + tid;

    float sv = spart[bt] + spart[BT + bt] + spart[2l * BT + bt] + spart[3l * BT + bt];
    s_ws[bt] = sv;
    float ev = __expf(sv);
    el[tid] = ev;
    // per-chunk e total: wave reduce (64) + 2-wave combine
    float r = ev;
    #pragma unroll
    for (int off = 1; off < 64; off <<= 1) r += __shfl_xor(r, off);
    if ((tid & 63) == 0) wred[tid >> 6] = r;
    __syncthreads();
    if (tid == 0) esum[b * NCHUNK + c] = wred[0] + wred[1];

    const _Float16* xb = xh + ((long)b * TLEN + c * CHUNK) * DIM;
    float a0 = 0.f, a1 = 0.f, a2 = 0.f, a3 = 0.f;
    for (int t = 0; t < CHUNK; ++t) {
        h4 xv = *(const h4*)(xb + (long)t * DIM + tid * 4);
        float wgt = el[t];
        a0 += wgt * (float)xv[0];
        a1 += wgt * (float)xv[1];
        a2 += wgt * (float)xv[2];
        a3 += wgt * (float)xv[3];
    }
    float4 o = {a0, a1, a2, a3};
    ((float4*)(csum + ((long)(b * NCHUNK + c)) * DIM))[tid] = o;
}

// ---------------------------------------------------------------------------
// Kernel 3: chunk_scan'. Per b: exclusive scan csum over c (512 lanes, tid<512)
// and exclusive scan esum over c (one wave, tid in [512,576), shfl scan).
// ---------------------------------------------------------------------------
__global__ __launch_bounds__(576) void chunk_scan_kernel(
    float* __restrict__ csum, float* __restrict__ esum)
{
    const int b = blockIdx.x;
    const int tid = threadIdx.x;
    if (tid < 512) {
        const int d = tid;
        float run = 0.f;
        #pragma unroll 8
        for (int c = 0; c < NCHUNK; ++c) {
            float* p = csum + ((long)(b * NCHUNK + c)) * DIM + d;
            float v = *p;
            *p = run;
            run += v;
        }
    } else {
        const int lane = tid - 512;          // 0..63 == chunk id
        float v = esum[b * NCHUNK + lane];
        const float own = v;
        #pragma unroll
        for (int off = 1; off < 64; off <<= 1) {
            float u = __shfl_up(v, off);
            if (lane >= off) v += u;
        }
        esum[b * NCHUNK + lane] = v - own;   // exclusive prefix
    }
}

// ---------------------------------------------------------------------------
// Kernel 4: context'. Recompute e[t] from s (ws), carry running den from the
// chunk-exclusive esum; out[b,t,d] = (csum_excl + running num) / running den.
// ---------------------------------------------------------------------------
__global__ __launch_bounds__(128) void context_kernel(
    const float* __restrict__ x, const float* __restrict__ s_ws,
    const float* __restrict__ esum, const float* __restrict__ csum,
    float* __restrict__ out)
{
    __shared__ float el[CHUNK];
    const int c = blockIdx.x, b = blockIdx.y;
    const int tid = threadIdx.x;
    el[tid] = __expf(s_ws[(long)b * TLEN + c * CHUNK + tid]);
    __syncthreads();
    float dacc = esum[b * NCHUNK + c];       // exclusive den prefix
    const float4* xb = (const float4*)(x + ((long)b * TLEN + c * CHUNK) * DIM);
    float4* ob = (float4*)(out + ((long)b * TLEN + c * CHUNK) * DIM);
    float4 acc = ((const float4*)(csum + ((long)(b * NCHUNK + c)) * DIM))[tid];
    for (int t = 0; t < CHUNK; ++t) {
        float4 xv = xb[t * (DIM / 4) + tid];
        float wv = el[t];
        dacc += wv;
        acc.x += wv * xv.x; acc.y += wv * xv.y;
        acc.z += wv * xv.z; acc.w += wv * xv.w;
        float inv = __fdividef(1.0f, dacc);
        float4 o = {acc.x * inv, acc.y * inv, acc.z * inv, acc.w * inv};
        ob[t * (DIM / 4) + tid] = o;
    }
}

// ---------------------------------------------------------------------------
extern "C" void kernel_launch(void* const* d_in, const int* in_sizes, int n_in,
                              void* d_out, int out_size, void* d_ws, size_t ws_size,
                              hipStream_t stream)
{
    const float* x  = (const float*)d_in[0];   // [4,8192,512]
    const float* W1 = (const float*)d_in[1];   // [512,512] row-major [e][d]
    const float* b1 = (const float*)d_in[2];   // [512]
    const float* w2 = (const float*)d_in[3];   // [512]
    // d_in[4] = b2 scalar: softmax shift-invariant, unused.
    float* out = (float*)d_out;

    float* ws   = (float*)d_ws;
    float* s_ws = ws;                       // [32768]
    float* csum = ws + BT;                  // [4*64*512] = 131072
    float* esum = ws + BT + 4 * NCHUNK * DIM;   // [4*64]

    // fp16 operands + spart live in d_out (67 MB): all consumed before the
    // final context_kernel overwrites d_out with the real output.
    _Float16* hbuf = (_Float16*)d_out;
    const _Float16* xh = hbuf;                              // 16.7M halfs
    const _Float16* wh = hbuf + (long)BT * DIM;             // 262K halfs
    float* spart = (float*)(hbuf + (long)BT * DIM + DIM * DIM);  // [4][32768]

    const long total4 = ((long)BT * DIM + (long)DIM * DIM) / 4;
    const int convBlocks = (int)((total4 + 255) / 256);

    convert_kernel<<<convBlocks, 256, 0, stream>>>(x, W1, hbuf);
    score_mfma_kernel<<<(BT / BM) * 4, 256, 0, stream>>>(xh, wh, b1, w2, spart);
    chunk_sum_kernel<<<dim3(NCHUNK, BATCH), 128, 0, stream>>>(xh, spart, s_ws, csum, esum);
    chunk_scan_kernel<<<BATCH, 576, 0, stream>>>(csum, esum);
    context_kernel<<<dim3(NCHUNK, BATCH), 128, 0, stream>>>(x, s_ws, esum, csum, out);
}